// Round 13
// baseline (202.443 us; speedup 1.0000x reference)
//
#include <hip/hip_runtime.h>
#include <math.h>

#define NT 16384     // tokens
#define NE 4096      // embed
#define NX 64        // experts
#define TK 8         // top-k

#define BM 32
#define NBLK (NT / BM)        // 512 blocks
#define NSTEP 64              // K-steps of BK=64

#define RO_SIZE (NT * NX)
#define TI_OFF  RO_SIZE
#define AUX_IDX (RO_SIZE + NT * TK)

#define MAXFLAG 8192
// ws float layout: [0]=flag_cnt, [1..1+MAXFLAG)=flag_list,
// ps_blk[512][64], fr_blk[512][64], lse2_blk[512], then bpack (bytes)
#define PSB_IDX 8256
#define FRB_IDX (PSB_IDX + NBLK * 64)
#define L2B_IDX (FRB_IDX + NBLK * 64)
#define WS_FLOATS (L2B_IDX + NBLK)
#define BPACK_OFF (((WS_FLOATS * 4) + 255) & ~255)
#define BPACK_USHORTS (128 * 4 * 2 * 128 * 8)   // 1M ushorts (2MB)
#define WS_NEED ((size_t)BPACK_OFF + (size_t)BPACK_USHORTS * 2)

#define DELTA_FP32 5e-5f
#define DELTA_BF16 2.5e-4f   // bf16x3 sigma ~1.5-2e-5, >12-sigma margin (verified r2-r12)

typedef __attribute__((ext_vector_type(8))) short bf16x8_t;
typedef __attribute__((ext_vector_type(4))) float f32x4_t;
typedef __attribute__((ext_vector_type(16))) float f32x16_t;

__device__ __forceinline__ float neginf() { return __int_as_float(0xff800000); }

__device__ __forceinline__ unsigned short bf16_trunc(float f) {
    return (unsigned short)(__float_as_uint(f) >> 16);
}
__device__ __forceinline__ unsigned short bf16_rtn(float f) {
    unsigned u = __float_as_uint(f);
    unsigned r = u + 0x7fffu + ((u >> 16) & 1u);
    return (unsigned short)(r >> 16);
}
__device__ __forceinline__ float bf16_to_f(unsigned short h) {
    return __uint_as_float(((unsigned)h) << 16);
}

// cheap 4-float split: hi = trunc bf16 (v_perm pack), lo = trunc bf16 of (f - hi)
__device__ __forceinline__ void split4(const float4& f,
                                       unsigned& h0, unsigned& h1,
                                       unsigned& l0, unsigned& l1) {
    unsigned u0 = __float_as_uint(f.x), u1 = __float_as_uint(f.y);
    unsigned u2 = __float_as_uint(f.z), u3 = __float_as_uint(f.w);
    h0 = __builtin_amdgcn_perm(u1, u0, 0x07060302u);   // {bf16(f.x), bf16(f.y)}
    h1 = __builtin_amdgcn_perm(u3, u2, 0x07060302u);
    float g0 = f.x - __uint_as_float(u0 & 0xffff0000u);
    float g1 = f.y - __uint_as_float(u1 & 0xffff0000u);
    float g2 = f.z - __uint_as_float(u2 & 0xffff0000u);
    float g3 = f.w - __uint_as_float(u3 & 0xffff0000u);
    l0 = __builtin_amdgcn_perm(__float_as_uint(g1), __float_as_uint(g0), 0x07060302u);
    l1 = __builtin_amdgcn_perm(__float_as_uint(g3), __float_as_uint(g2), 0x07060302u);
}

// async 16B global->LDS DMA (LDS dest = wave-uniform base + lane*16)
#define GLOAD16(GP, LP) __builtin_amdgcn_global_load_lds(                     \
    (const __attribute__((address_space(1))) void*)(GP),                      \
    (__attribute__((address_space(3))) void*)(LP), 16, 0, 0)

// ---------------------------------------------------------------------------
// prep: pack w_route|w_noise into fragment-major hi/lo bf16 (verified r4-r12):
// chunk(kt,kq,h,col) = ((kt*4+kq)*2 + h)*128 + col, 8 ushorts per chunk.
// ---------------------------------------------------------------------------
__global__ __launch_bounds__(512) void prep_w_kernel(
    const float* __restrict__ w_route, const float* __restrict__ w_noise,
    unsigned short* __restrict__ bp)
{
    const int kt = blockIdx.x;
    const int t = threadIdx.x;
    const int col = t & 127;
    const int kq = t >> 7;
    const float* src = (col < NX) ? (w_route + col) : (w_noise + (col - NX));
    const int kbase = kt * 32 + kq * 8;
    bf16x8_t h8, l8;
    #pragma unroll
    for (int i = 0; i < 8; ++i) {
        float v = src[(size_t)(kbase + i) * NX];
        unsigned short hh = bf16_trunc(v);
        h8[i] = (short)hh;
        l8[i] = (short)bf16_rtn(v - bf16_to_f(hh));
    }
    unsigned short* base = bp + ((size_t)((kt * 4 + kq) * 2) * 128 + col) * 8;
    *(bf16x8_t*)base = h8;                 // h = 0
    *(bf16x8_t*)(base + 128 * 8) = l8;     // h = 1
}

// ---------------------------------------------------------------------------
// Fused GEMM + routing, 32x32x16 MFMA, counted-vmcnt pipeline (T3/T4):
// raw s_barrier, lgkmcnt(0)+vmcnt(1) at step tail -> rx(t+2) HBM load stays
// in flight across barriers; B DMA covered by one COMPUTE.
// 8 waves = cgq{4} x kh{2}; 6 MFMA(32x32)/wave/step, 8 ds_read_b128.
// grid 512 x 512 thr, 80KB LDS -> 2 blocks/CU.
// ---------------------------------------------------------------------------
__global__ __launch_bounds__(512, 4) void fused32_kernel(
    const float* __restrict__ x,
    const unsigned short* __restrict__ bp,
    const float* __restrict__ b_route, const float* __restrict__ b_noise,
    const float* __restrict__ noise,
    float* __restrict__ out,
    float* __restrict__ ps_blk, float* __restrict__ fr_blk,
    float* __restrict__ lse2_blk,
    int* __restrict__ flag_cnt, int* __restrict__ flag_list)
{
    __shared__ __align__(16) char ldsraw[81920];   // A bf16 dbuf 16KB | B dbuf 64KB

    const int tid = threadIdx.x;
    const int wid = tid >> 6;
    const int lane = tid & 63;
    const int l31 = lane & 31;
    const int lhi = lane >> 5;         // k-octet selector within a 16-k slice
    const int cgq = wid & 3;           // col-tile (32 cols each)
    const int kh = wid >> 2;           // k-half (0..1)
    const int bm = blockIdx.x * BM;

    // ---- A staging map (verified r11/r12) ----
    const int srow = tid >> 4;          // 0..31
    const int sq = tid & 15;            // k = sq*4 .. +3
    const int skc = sq >> 1;            // 8-k chunk 0..7
    const int shalf = sq & 1;
    const int srl = srow & 15;
    const int offA = srow * 256 + ((skc ^ srl) << 4) + shalf * 8;
    const float* sxa = x + (size_t)(bm + srow) * NE + sq * 4;

    char* ldsB = ldsraw + 16384;
    char* dB = ldsB + tid * 16;

    #define STAGE_B(BUF, ST) do {                                             \
        const unsigned short* sB_ = bp + (size_t)(ST) * 16384 + tid * 8;      \
        char* dB_ = dB + (BUF) * 32768;                                       \
        GLOAD16(sB_,         dB_);                                            \
        GLOAD16(sB_ + 4096,  dB_ + 8192);                                     \
        GLOAD16(sB_ + 8192,  dB_ + 16384);                                    \
        GLOAD16(sB_ + 12288, dB_ + 24576);                                    \
    } while (0)

    #define WRITE_A(BUF, RX) do {                                             \
        unsigned h0_, h1_, l0_, l1_;                                          \
        split4(RX, h0_, h1_, l0_, l1_);                                       \
        const int ob_ = (BUF) * 8192;                                         \
        *(int2*)(ldsraw + ob_ + offA)         = make_int2((int)h0_, (int)h1_);\
        *(int2*)(ldsraw + ob_ + (offA ^ 128)) = make_int2((int)l0_, (int)l1_);\
    } while (0)

    f32x16_t acc;
    #pragma unroll
    for (int i = 0; i < 16; ++i) acc[i] = 0.f;

    // A read offsets (32x32x16 frag: lane=row+32*(k>>3), 8 contiguous k)
    const int r15 = l31 & 15;
    const int adrA0 = l31 * 256 + (((4 * kh + 0 + lhi) ^ r15) << 4);
    const int adrA1 = l31 * 256 + (((4 * kh + 2 + lhi) ^ r15) << 4);
    const int offB = kh * 16384 + lhi * 4096 + (cgq * 32 + l31) * 16;

    #define COMPUTE(CUR) do {                                                 \
        const char* aB_ = ldsraw + (CUR) * 8192;                              \
        const char* bT_ = ldsB + (CUR) * 32768;                               \
        bf16x8_t ah0 = *(const bf16x8_t*)(aB_ + adrA0);                       \
        bf16x8_t al0 = *(const bf16x8_t*)(aB_ + (adrA0 ^ 128));               \
        bf16x8_t bh0 = *(const bf16x8_t*)(bT_ + offB);                        \
        bf16x8_t bl0 = *(const bf16x8_t*)(bT_ + offB + 2048);                 \
        acc = __builtin_amdgcn_mfma_f32_32x32x16_bf16(ah0, bh0, acc, 0, 0, 0);\
        acc = __builtin_amdgcn_mfma_f32_32x32x16_bf16(al0, bh0, acc, 0, 0, 0);\
        acc = __builtin_amdgcn_mfma_f32_32x32x16_bf16(ah0, bl0, acc, 0, 0, 0);\
        bf16x8_t ah1 = *(const bf16x8_t*)(aB_ + adrA1);                       \
        bf16x8_t al1 = *(const bf16x8_t*)(aB_ + (adrA1 ^ 128));               \
        bf16x8_t bh1 = *(const bf16x8_t*)(bT_ + offB + 8192);                 \
        bf16x8_t bl1 = *(const bf16x8_t*)(bT_ + offB + 8192 + 2048);          \
        acc = __builtin_amdgcn_mfma_f32_32x32x16_bf16(ah1, bh1, acc, 0, 0, 0);\
        acc = __builtin_amdgcn_mfma_f32_32x32x16_bf16(al1, bh1, acc, 0, 0, 0);\
        acc = __builtin_amdgcn_mfma_f32_32x32x16_bf16(ah1, bl1, acc, 0, 0, 0);\
    } while (0)

    // step tail: own ds_writes visible, B(next) DMA complete, rx stays in flight
    #define STEP_TAIL() do {                                                  \
        asm volatile("s_waitcnt lgkmcnt(0)" ::: "memory");                    \
        asm volatile("s_waitcnt vmcnt(1)" ::: "memory");                      \
        __builtin_amdgcn_s_barrier();                                         \
        __builtin_amdgcn_sched_barrier(0);                                    \
    } while (0)

    // ---- prologue: A(0) write, B(0) DMA, rx=A(1) in flight ----
    float4 rxC, rxN;
    rxC = *(const float4*)(sxa);
    WRITE_A(0, rxC);
    STAGE_B(0, 0);
    __builtin_amdgcn_sched_barrier(0);
    rxC = *(const float4*)(sxa + 64);     // A(1)
    __builtin_amdgcn_sched_barrier(0);
    STEP_TAIL();                          // B(0)+A(0) ready; rx A(1) in flight

    for (int t = 0; t < NSTEP; t += 2) {
        // even step: consume buf0
        {
            const int tn1 = (t + 1 < NSTEP) ? t + 1 : NSTEP - 1;
            const int tn2 = (t + 2 < NSTEP) ? t + 2 : NSTEP - 1;
            STAGE_B(1, tn1);
            __builtin_amdgcn_sched_barrier(0);
            rxN = *(const float4*)(sxa + tn2 * 64);    // A(t+2)
            __builtin_amdgcn_sched_barrier(0);
            COMPUTE(0);
            WRITE_A(1, rxC);                           // waits rx A(t+1) only
            STEP_TAIL();
        }
        // odd step: consume buf1
        {
            const int tt = t + 1;
            const int tn1 = (tt + 1 < NSTEP) ? tt + 1 : NSTEP - 1;
            const int tn2 = (tt + 2 < NSTEP) ? tt + 2 : NSTEP - 1;
            STAGE_B(0, tn1);
            __builtin_amdgcn_sched_barrier(0);
            rxC = *(const float4*)(sxa + tn2 * 64);    // A(tt+2)
            __builtin_amdgcn_sched_barrier(0);
            COMPUTE(1);
            WRITE_A(0, rxN);
            STEP_TAIL();
        }
    }
    #undef STAGE_B
    #undef WRITE_A
    #undef COMPUTE
    #undef STEP_TAIL

    __syncthreads();   // FULL drain (leftover DMA + rx) before LDS reuse

    // per-(cgq,kh) 32x32 patch -> part[kh] (C/D map m74/m101:
    // col = lane&31, row = (reg&3) + 8*(reg>>2) + 4*(lane>>5))
    float (*part)[32][132] = (float (*)[32][132])ldsraw;   // 33792 B
    #pragma unroll
    for (int r = 0; r < 16; ++r) {
        int row = (r & 3) + 8 * (r >> 2) + 4 * lhi;
        part[kh][row][cgq * 32 + l31] = acc[r];
    }
    __syncthreads();

    // ---- routing epilogue (verified r1-r12): 8 waves x 4 tokens ----
    const float br = b_route[lane];
    const float bnv = b_noise[lane];
    float ps_l = 0.f, fr_l = 0.f, l2_l = 0.f;

    for (int tt = 0; tt < 4; ++tt) {
        const int tok = wid * 4 + tt;
        const int gt  = bm + tok;
        float lr = part[0][tok][lane] + part[1][tok][lane] + br;
        float ln = part[0][tok][64 + lane] + part[1][tok][64 + lane] + bnv;
        float nz = noise[(size_t)gt * NX + lane];
        float sp = fmaxf(ln, 0.f) + log1pf(expf(-fabsf(ln)));   // softplus
        float v  = lr + nz * sp;                                 // noisy logit

        // top-9 iterative wave argmax (ties -> lower index)
        float vv = v;
        float tv[9]; int ti[9];
        #pragma unroll
        for (int s = 0; s < 9; ++s) {
            float mv = vv; int mi = lane;
            #pragma unroll
            for (int off = 32; off > 0; off >>= 1) {
                float ov = __shfl_xor(mv, off);
                int   oi = __shfl_xor(mi, off);
                if (ov > mv || (ov == mv && oi < mi)) { mv = ov; mi = oi; }
            }
            tv[s] = mv; ti[s] = mi;
            if (lane == mi) vv = neginf();
        }

        float ming = 1e30f;
        #pragma unroll
        for (int s = 0; s < 8; ++s) ming = fminf(ming, tv[s] - tv[s + 1]);
        if (lane == 0 && ming < DELTA_BF16) {
            int p = atomicAdd(flag_cnt, 1);
            if (p < MAXFLAG) flag_list[p] = gt;
        }

        const float m0 = tv[0];
        float e8[8], s8 = 0.f;
        #pragma unroll
        for (int s = 0; s < 8; ++s) { e8[s] = expf(tv[s] - m0); s8 += e8[s]; }
        float r = 0.f;
        #pragma unroll
        for (int s = 0; s < 8; ++s) if (ti[s] == lane) r = e8[s] / s8;
        out[(size_t)gt * NX + lane] = r;
        if (lane < TK) out[TI_OFF + (size_t)gt * TK + lane] = (float)ti[lane];

        float p = expf(v - m0);
        float s64 = p;
        #pragma unroll
        for (int off = 32; off > 0; off >>= 1) s64 += __shfl_xor(s64, off);
        ps_l += p / s64;
        if (lane == 0) { float lse = m0 + logf(s64); l2_l += lse * lse; }

        unsigned tm8 = 0;
        #pragma unroll
        for (int s = 0; s < 8; ++s) if (ti[s] < TK) tm8 |= (1u << ti[s]);
        #pragma unroll
        for (int s = 0; s < 8; ++s)
            if (ti[s] == lane && ((tm8 >> s) & 1u)) fr_l += 1.f;
    }

    // ---- privatized per-block stats (no global atomics) ----
    float* sps = (float*)(ldsraw + 34816);          // [8][64]
    float* sfr = (float*)(ldsraw + 34816 + 2048);   // [8][64]
    float* sl2 = (float*)(ldsraw + 34816 + 4096);   // [8]
    sps[wid * 64 + lane] = ps_l;
    sfr[wid * 64 + lane] = fr_l;
    if (lane == 0) sl2[wid] = l2_l;
    __syncthreads();
    if (wid == 0) {
        float a = 0.f, b = 0.f;
        #pragma unroll
        for (int w = 0; w < 8; ++w) {
            a += sps[w * 64 + lane];
            b += sfr[w * 64 + lane];
        }
        ps_blk[(size_t)blockIdx.x * 64 + lane] = a;
        fr_blk[(size_t)blockIdx.x * 64 + lane] = b;
        if (lane == 0) {
            float z = 0.f;
            #pragma unroll
            for (int w = 0; w < 8; ++w) z += sl2[w];
            lse2_blk[blockIdx.x] = z;
        }
    }
}

// ---------------------------------------------------------------------------
// Fallback fp32-VALU fused kernel (round-1 verified) for small ws_size.
// ---------------------------------------------------------------------------
#define FBM 64
#define FBN 128
#define FBK 32
#define XPITCH (FBM + 4)
__global__ __launch_bounds__(256) void fused_router_kernel(
    const float* __restrict__ x,
    const float* __restrict__ w_route, const float* __restrict__ b_route,
    const float* __restrict__ w_noise, const float* __restrict__ b_noise,
    const float* __restrict__ noise,
    float* __restrict__ out,
    float* __restrict__ ps_acc, float* __restrict__ fr_acc,
    float* __restrict__ lse2_acc,
    int* __restrict__ flag_cnt, int* __restrict__ flag_list)
{
    __shared__ float smem[FBM * FBN];
    float* xs  = smem;
    float* wst = smem + FBK * XPITCH;
    const int tid = threadIdx.x;
    const int block_m = blockIdx.x * FBM;
    const int row0 = (tid >> 5) * 8;
    const int col0 = (tid & 31) * 4;
    float acc[8][4];
    #pragma unroll
    for (int i = 0; i < 8; ++i)
        #pragma unroll
        for (int j = 0; j < 4; ++j) acc[i][j] = 0.f;
    float4 px[2], pw[4];
    {
        #pragma unroll
        for (int s = 0; s < 2; ++s) {
            int f = tid + s * 256, r = f >> 3, kqv = f & 7;
            px[s] = *reinterpret_cast<const float4*>(x + (size_t)(block_m + r) * NE + kqv * 4);
        }
        #pragma unroll
        for (int s = 0; s < 4; ++s) {
            int f = tid + s * 256, kk = f >> 5, c4 = (f & 31) * 4;
            const float* src = (c4 < NX) ? (w_route + (size_t)kk * NX + c4)
                                         : (w_noise + (size_t)kk * NX + (c4 - NX));
            pw[s] = *reinterpret_cast<const float4*>(src);
        }
    }
    for (int t = 0; t < NE / FBK; ++t) {
        __syncthreads();
        #pragma unroll
        for (int s = 0; s < 2; ++s) {
            int f = tid + s * 256, r = f >> 3, kqv = f & 7;
            xs[(kqv * 4 + 0) * XPITCH + r] = px[s].x;
            xs[(kqv * 4 + 1) * XPITCH + r] = px[s].y;
            xs[(kqv * 4 + 2) * XPITCH + r] = px[s].z;
            xs[(kqv * 4 + 3) * XPITCH + r] = px[s].w;
        }
        #pragma unroll
        for (int s = 0; s < 4; ++s) {
            int f = tid + s * 256, kk = f >> 5, c4 = (f & 31) * 4;
            *reinterpret_cast<float4*>(&wst[kk * FBN + c4]) = pw[s];
        }
        __syncthreads();
        if (t + 1 < NE / FBK) {
            const int k0 = (t + 1) * FBK;
            #pragma unroll
            for (int s = 0; s < 2; ++s) {
                int f = tid + s * 256, r = f >> 3, kqv = f & 7;
                px[s] = *reinterpret_cast<const float4*>(x + (size_t)(block_m + r) * NE + k0 + kqv * 4);
            }
            #pragma unroll
            for (int s = 0; s < 4; ++s) {
                int f = tid + s * 256, kk = f >> 5, c4 = (f & 31) * 4;
                const float* src = (c4 < NX) ? (w_route + (size_t)(k0 + kk) * NX + c4)
                                             : (w_noise + (size_t)(k0 + kk) * NX + (c4 - NX));
                pw[s] = *reinterpret_cast<const float4*>(src);
            }
        }
        #pragma unroll
        for (int k = 0; k < FBK; ++k) {
            float4 xa = *reinterpret_cast<const float4*>(&xs[k * XPITCH + row0]);
            float4 xb = *reinterpret_cast<const float4*>(&xs[k * XPITCH + row0 + 4]);
            float4 wv = *reinterpret_cast<const float4*>(&wst[k * FBN + col0]);
            float xf[8] = {xa.x, xa.y, xa.z, xa.w, xb.x, xb.y, xb.z, xb.w};
            float wf[4] = {wv.x, wv.y, wv.z, wv.w};
            #pragma unroll
            for (int i = 0; i < 8; ++i)
                #pragma unroll
                for (int j = 0; j < 4; ++j)
                    acc[i][j] = fmaf(xf[i], wf[j], acc[i][j]);
        }
    }
    __syncthreads();
    #pragma unroll
    for (int i = 0; i < 8; ++i) {
        float4 v = make_float4(acc[i][0], acc[i][1], acc[i][2], acc[i][3]);
        *reinterpret_cast<float4*>(&smem[(row0 + i) * FBN + col0]) = v;
    }
    __syncthreads();
    const int wave = tid >> 6;
    const int lane = tid & 63;
    const float br = b_route[lane];
    const float bnv = b_noise[lane];
    float ps_l = 0.f, fr_l = 0.f, l2_l = 0.f;
    for (int tt = 0; tt < FBM / 4; ++tt) {
        const int tok = wave * (FBM / 4) + tt;
        const int gt  = block_m + tok;
        float lr = smem[tok * FBN + lane] + br;
        float ln = smem[tok * FBN + NX + lane] + bnv;
        float nz = noise[(size_t)gt * NX + lane];
        float sp = fmaxf(ln, 0.f) + log1pf(expf(-fabsf(ln)));
        float v  = lr + nz * sp;
        float vv = v;
        float tv[9]; int ti[9];
        #pragma unroll
        for (int s = 0; s < 9; ++s) {
            float mv = vv; int mi = lane;
            #pragma unroll
            for (int off = 32; off > 0; off >>= 1) {
                float ov = __shfl_xor(mv, off);
                int   oi = __shfl_xor(mi, off);
                if (ov > mv || (ov == mv && oi < mi)) { mv = ov; mi = oi; }
            }
            tv[s] = mv; ti[s] = mi;
            if (lane == mi) vv = neginf();
        }
        float ming = 1e30f;
        #pragma unroll
        for (int s = 0; s < 8; ++s) ming = fminf(ming, tv[s] - tv[s + 1]);
        if (lane == 0 && ming < DELTA_FP32) {
            int p = atomicAdd(flag_cnt, 1);
            if (p < MAXFLAG) flag_list[p] = gt;
        }
        const float m0 = tv[0];
        float e8[8], s8 = 0.f;
        #pragma unroll
        for (int s = 0; s < 8; ++s) { e8[s] = expf(tv[s] - m0); s8 += e8[s]; }
        float r = 0.f;
        #pragma unroll
        for (int s = 0; s < 8; ++s) if (ti[s] == lane) r = e8[s] / s8;
        out[(size_t)gt * NX + lane] = r;
        if (lane < TK) out[TI_OFF + (size_t)gt * TK + lane] = (float)ti[lane];
        float p = expf(v - m0);
        float s64 = p;
        #pragma unroll
        for (int off = 32; off > 0; off >>= 1) s64 += __shfl_xor(s64, off);
        ps_l += p / s64;
        if (lane == 0) { float lse = m0 + logf(s64); l2_l += lse * lse; }
        unsigned tm8 = 0;
        #pragma unroll
        for (int s = 0; s < 8; ++s) if (ti[s] < TK) tm8 |= (1u << ti[s]);
        #pragma unroll
        for (int s = 0; s < 8; ++s)
            if (ti[s] == lane && ((tm8 >> s) & 1u)) fr_l += 1.f;
    }
    atomicAdd(&ps_acc[lane], ps_l);
    atomicAdd(&fr_acc[lane], fr_l);
    if (lane == 0) atomicAdd(lse2_acc, l2_l);
}

// ---------------------------------------------------------------------------
// fp64 repair of near-tie tokens (verified r3-r12)
// ---------------------------------------------------------------------------
__global__ __launch_bounds__(256) void refine_kernel(
    const float* __restrict__ x, const float* __restrict__ w_route,
    const float* __restrict__ b_route, const float* __restrict__ w_noise,
    const float* __restrict__ b_noise, const float* __restrict__ noise,
    float* __restrict__ out, const int* __restrict__ flag_cnt,
    const int* __restrict__ flag_list)
{
    __shared__ double red[8][64];
    const int tid = threadIdx.x;
    const int lane = tid & 63, wq = tid >> 6;
    int nf = *flag_cnt; if (nf > MAXFLAG) nf = MAXFLAG;
    for (int fi = blockIdx.x; fi < nf; fi += gridDim.x) {
        const int gt = flag_list[fi];
        const float* xr = x + (size_t)gt * NE + wq * 1024;
        const float* wr = w_route + (size_t)wq * 1024 * NX;
        const float* wn = w_noise + (size_t)wq * 1024 * NX;
        double ar0 = 0, ar1 = 0, an0 = 0, an1 = 0;
        for (int k = 0; k < 1024; k += 2) {
            double x0 = xr[k], x1 = xr[k + 1];
            ar0 += x0 * (double)wr[(size_t)k * NX + lane];
            ar1 += x1 * (double)wr[(size_t)(k + 1) * NX + lane];
            an0 += x0 * (double)wn[(size_t)k * NX + lane];
            an1 += x1 * (double)wn[(size_t)(k + 1) * NX + lane];
        }
        red[wq * 2][lane]     = ar0 + ar1;
        red[wq * 2 + 1][lane] = an0 + an1;
        __syncthreads();
        if (tid < 64) {
            double lr = red[0][lane] + red[2][lane] + red[4][lane] + red[6][lane]
                      + (double)b_route[lane];
            double ln = red[1][lane] + red[3][lane] + red[5][lane] + red[7][lane]
                      + (double)b_noise[lane];
            double nz = (double)noise[(size_t)gt * NX + lane];
            double sp = (ln > 0.0) ? (ln + log1p(exp(-ln))) : log1p(exp(ln));
            double v  = lr + nz * sp;
            double vv = v;
            double tv[8]; int ti[8];
            #pragma unroll
            for (int s = 0; s < 8; ++s) {
                double mv = vv; int mi = lane;
                #pragma unroll
                for (int off = 32; off > 0; off >>= 1) {
                    double ov = __shfl_xor(mv, off);
                    int    oi = __shfl_xor(mi, off);
                    if (ov > mv || (ov == mv && oi < mi)) { mv = ov; mi = oi; }
                }
                tv[s] = mv; ti[s] = mi;
                if (lane == mi) vv = -1.0e300;
            }
            double m0 = tv[0], s8 = 0.0, e8[8];
            #pragma unroll
            for (int s = 0; s < 8; ++s) { e8[s] = exp(tv[s] - m0); s8 += e8[s]; }
            float r = 0.f;
            #pragma unroll
            for (int s = 0; s < 8; ++s) if (ti[s] == lane) r = (float)(e8[s] / s8);
            out[(size_t)gt * NX + lane] = r;
            if (lane < TK) out[TI_OFF + (size_t)gt * TK + lane] = (float)ti[lane];
        }
        __syncthreads();
    }
}

// ---------------------------------------------------------------------------
// finalize: deterministic reduce of per-block stats, compute aux loss
// ---------------------------------------------------------------------------
__global__ __launch_bounds__(512) void finalize_kernel(
    const float* __restrict__ ps_blk, const float* __restrict__ fr_blk,
    const float* __restrict__ lse2_blk, float* __restrict__ out)
{
    __shared__ float sps[8][64], sfr[8][64], sl2[512];
    const int t = threadIdx.x;
    const int e = t & 63, g = t >> 6;
    float a = 0.f, b = 0.f;
    for (int blk = g; blk < NBLK; blk += 8) {
        a += ps_blk[(size_t)blk * 64 + e];
        b += fr_blk[(size_t)blk * 64 + e];
    }
    sps[g][e] = a;
    sfr[g][e] = b;
    sl2[t] = lse2_blk[t];
    __syncthreads();
    if (t < 64) {
        float p = 0.f, f = 0.f;
        #pragma unroll
        for (int gg = 0; gg < 8; ++gg) { p += sps[gg][t]; f += sfr[gg][t]; }
        float z = 0.f;
        #pragma unroll
        for (int i = 0; i < 8; ++i) z += sl2[t * 8 + i];
        float sp = p, sf = f, sz = z;
        #pragma unroll
        for (int off = 32; off > 0; off >>= 1) {
            sp += __shfl_xor(sp, off);
            sf += __shfl_xor(sf, off);
            sz += __shfl_xor(sz, off);
        }
        float d = (p / fmaxf(sp, 1e-12f)) * (f / fmaxf(sf, 1e-12f));
        #pragma unroll
        for (int off = 32; off > 0; off >>= 1) d += __shfl_xor(d, off);
        if (t == 0)
            out[AUX_IDX] = 64.f * d + 0.1f * (sz / (float)NT);
    }
}

// ---------------------------------------------------------------------------
extern "C" void kernel_launch(void* const* d_in, const int* in_sizes, int n_in,
                              void* d_out, int out_size, void* d_ws, size_t ws_size,
                              hipStream_t stream) {
    const float* x       = (const float*)d_in[0];
    const float* w_route = (const float*)d_in[1];
    const float* b_route = (const float*)d_in[2];
    const float* w_noise = (const float*)d_in[3];
    const float* b_noise = (const float*)d_in[4];
    const float* noise   = (const float*)d_in[5];
    float* out = (float*)d_out;

    float* wsf = (float*)d_ws;
    int* flag_cnt  = (int*)wsf;
    int* flag_list = (int*)(wsf + 1);
    float* ps_blk   = wsf + PSB_IDX;
    float* fr_blk   = wsf + FRB_IDX;
    float* lse2_blk = wsf + L2B_IDX;

    // zero flag region (cnt + list)
    hipMemsetAsync(d_ws, 0, (size_t)(1 + MAXFLAG) * sizeof(int), stream);

    if (ws_size >= WS_NEED) {
        unsigned short* bpack = (unsigned short*)((char*)d_ws + BPACK_OFF);
        prep_w_kernel<<<128, 512, 0, stream>>>(w_route, w_noise, bpack);
        fused32_kernel<<<NBLK, 512, 0, stream>>>(
            x, bpack, b_route, b_noise, noise, out,
            ps_blk, fr_blk, lse2_blk, flag_cnt, flag_list);
    } else {
        // fallback: zero whole stats region, atomic-accumulate into row 0
        hipMemsetAsync(ps_blk, 0,
                       (size_t)(WS_FLOATS - PSB_IDX) * sizeof(float), stream);
        fused_router_kernel<<<NT / FBM, 256, 0, stream>>>(
            x, w_route, b_route, w_noise, b_noise, noise, out,
            ps_blk, fr_blk, lse2_blk, flag_cnt, flag_list);
    }

    refine_kernel<<<1024, 256, 0, stream>>>(
        x, w_route, b_route, w_noise, b_noise, noise, out, flag_cnt, flag_list);

    finalize_kernel<<<1, 512, 0, stream>>>(ps_blk, fr_blk, lse2_blk, out);
}

// Round 15
// 199.921 us; speedup vs baseline: 1.0126x; 1.0126x over previous
//
#include <hip/hip_runtime.h>
#include <math.h>

#define NT 16384     // tokens
#define NE 4096      // embed
#define NX 64        // experts
#define TK 8         // top-k

#define BM 32
#define NBLK (NT / BM)        // 512 blocks
#define NSTEP 64              // K-steps of BK=64

#define RO_SIZE (NT * NX)
#define TI_OFF  RO_SIZE
#define AUX_IDX (RO_SIZE + NT * TK)

#define MAXFLAG 8192
// ws float layout: [0]=flag_cnt, [1..1+MAXFLAG)=flag_list,
// ps_blk[512][64], fr_blk[512][64], lse2_blk[512], then bpack (bytes)
#define PSB_IDX 8256
#define FRB_IDX (PSB_IDX + NBLK * 64)
#define L2B_IDX (FRB_IDX + NBLK * 64)
#define WS_FLOATS (L2B_IDX + NBLK)
#define BPACK_OFF (((WS_FLOATS * 4) + 255) & ~255)
#define BPACK_USHORTS (128 * 4 * 2 * 128 * 8)   // 1M ushorts (2MB)
#define WS_NEED ((size_t)BPACK_OFF + (size_t)BPACK_USHORTS * 2)

#define DELTA_FP32 5e-5f
#define DELTA_BF16 2.5e-4f   // bf16x3 sigma ~1.5-2e-5, >12-sigma margin (verified r2-r13)

typedef __attribute__((ext_vector_type(8))) short bf16x8_t;
typedef __attribute__((ext_vector_type(4))) float f32x4_t;
typedef __attribute__((ext_vector_type(16))) float f32x16_t;

__device__ __forceinline__ float neginf() { return __int_as_float(0xff800000); }

__device__ __forceinline__ unsigned short bf16_trunc(float f) {
    return (unsigned short)(__float_as_uint(f) >> 16);
}
__device__ __forceinline__ unsigned short bf16_rtn(float f) {
    unsigned u = __float_as_uint(f);
    unsigned r = u + 0x7fffu + ((u >> 16) & 1u);
    return (unsigned short)(r >> 16);
}
__device__ __forceinline__ float bf16_to_f(unsigned short h) {
    return __uint_as_float(((unsigned)h) << 16);
}

// cheap 4-float split: hi = trunc bf16 (v_perm pack), lo = trunc bf16 of (f - hi)
__device__ __forceinline__ void split4(const float4& f,
                                       unsigned& h0, unsigned& h1,
                                       unsigned& l0, unsigned& l1) {
    unsigned u0 = __float_as_uint(f.x), u1 = __float_as_uint(f.y);
    unsigned u2 = __float_as_uint(f.z), u3 = __float_as_uint(f.w);
    h0 = __builtin_amdgcn_perm(u1, u0, 0x07060302u);   // {bf16(f.x), bf16(f.y)}
    h1 = __builtin_amdgcn_perm(u3, u2, 0x07060302u);
    float g0 = f.x - __uint_as_float(u0 & 0xffff0000u);
    float g1 = f.y - __uint_as_float(u1 & 0xffff0000u);
    float g2 = f.z - __uint_as_float(u2 & 0xffff0000u);
    float g3 = f.w - __uint_as_float(u3 & 0xffff0000u);
    l0 = __builtin_amdgcn_perm(__float_as_uint(g1), __float_as_uint(g0), 0x07060302u);
    l1 = __builtin_amdgcn_perm(__float_as_uint(g3), __float_as_uint(g2), 0x07060302u);
}

// async 16B global->LDS DMA (LDS dest = wave-uniform base + lane*16)
#define GLOAD16(GP, LP) __builtin_amdgcn_global_load_lds(                     \
    (const __attribute__((address_space(1))) void*)(GP),                      \
    (__attribute__((address_space(3))) void*)(LP), 16, 0, 0)

// ---------------------------------------------------------------------------
// prep: pack w_route|w_noise into fragment-major hi/lo bf16 (verified r4-r13):
// chunk(kt,kq,h,col) = ((kt*4+kq)*2 + h)*128 + col, 8 ushorts per chunk.
// ---------------------------------------------------------------------------
__global__ __launch_bounds__(512) void prep_w_kernel(
    const float* __restrict__ w_route, const float* __restrict__ w_noise,
    unsigned short* __restrict__ bp)
{
    const int kt = blockIdx.x;
    const int t = threadIdx.x;
    const int col = t & 127;
    const int kq = t >> 7;
    const float* src = (col < NX) ? (w_route + col) : (w_noise + (col - NX));
    const int kbase = kt * 32 + kq * 8;
    bf16x8_t h8, l8;
    #pragma unroll
    for (int i = 0; i < 8; ++i) {
        float v = src[(size_t)(kbase + i) * NX];
        unsigned short hh = bf16_trunc(v);
        h8[i] = (short)hh;
        l8[i] = (short)bf16_rtn(v - bf16_to_f(hh));
    }
    unsigned short* base = bp + ((size_t)((kt * 4 + kq) * 2) * 128 + col) * 8;
    *(bf16x8_t*)base = h8;                 // h = 0
    *(bf16x8_t*)(base + 128 * 8) = l8;     // h = 1
}

// ---------------------------------------------------------------------------
// Fused GEMM + routing, 32x32x16 MFMA, 2 independent acc chains per wave.
// A: reg-staged (float4 -> split4 -> ds_write hi/lo, swizzled), dbuf 16KB,
// rx 2-deep. B: global_load_lds DMA dbuf 64KB.
// 8 waves = cgp{2 col-halves} x kh{4 k-quarters}; per wave/step:
// 2 A ds_reads, 4 B ds_reads, 6 MFMA interleaved across acc0/acc1.
// grid 512 x 512 thr, 80KB LDS -> 2 blocks/CU.
// ---------------------------------------------------------------------------
__global__ __launch_bounds__(512, 4) void fused32_kernel(
    const float* __restrict__ x,
    const unsigned short* __restrict__ bp,
    const float* __restrict__ b_route, const float* __restrict__ b_noise,
    const float* __restrict__ noise,
    float* __restrict__ out,
    float* __restrict__ ps_blk, float* __restrict__ fr_blk,
    float* __restrict__ lse2_blk,
    int* __restrict__ flag_cnt, int* __restrict__ flag_list)
{
    __shared__ __align__(16) char ldsraw[81920];   // A bf16 dbuf 16KB | B dbuf 64KB

    const int tid = threadIdx.x;
    const int wid = tid >> 6;
    const int lane = tid & 63;
    const int l31 = lane & 31;
    const int lhi = lane >> 5;         // k-octet selector within a 16-k slice
    const int cgp = wid & 1;           // col half (64 cols each)
    const int kh = wid >> 1;           // k-quarter (0..3): 16-k slice per step
    const int bm = blockIdx.x * BM;

    // ---- A staging map (verified r11-r13) ----
    const int srow = tid >> 4;          // 0..31
    const int sq = tid & 15;            // k = sq*4 .. +3
    const int skc = sq >> 1;
    const int shalf = sq & 1;
    const int srl = srow & 15;
    // A layout per buf: [row32][16 chunks x 16B]; hi chunk c=kc, lo c=8+kc;
    // stored at c ^ (row&15); lo = hi offset ^ 128.
    const int offA = srow * 256 + ((skc ^ srl) << 4) + shalf * 8;
    const float* sxa = x + (size_t)(bm + srow) * NE + sq * 4;

    char* ldsB = ldsraw + 16384;
    char* dB = ldsB + tid * 16;

    #define STAGE_B(BUF, ST) do {                                             \
        const unsigned short* sB_ = bp + (size_t)(ST) * 16384 + tid * 8;      \
        char* dB_ = dB + (BUF) * 32768;                                       \
        GLOAD16(sB_,         dB_);                                            \
        GLOAD16(sB_ + 4096,  dB_ + 8192);                                     \
        GLOAD16(sB_ + 8192,  dB_ + 16384);                                    \
        GLOAD16(sB_ + 12288, dB_ + 24576);                                    \
    } while (0)

    #define WRITE_A(BUF, RX) do {                                             \
        unsigned h0_, h1_, l0_, l1_;                                          \
        split4(RX, h0_, h1_, l0_, l1_);                                       \
        const int ob_ = (BUF) * 8192;                                         \
        *(int2*)(ldsraw + ob_ + offA)         = make_int2((int)h0_, (int)h1_);\
        *(int2*)(ldsraw + ob_ + (offA ^ 128)) = make_int2((int)l0_, (int)l1_);\
    } while (0)

    f32x16_t acc0, acc1;
    #pragma unroll
    for (int i = 0; i < 16; ++i) { acc0[i] = 0.f; acc1[i] = 0.f; }

    // A read offset (32x32x16 frag: lane=row+32*(k>>3), 8 contiguous k):
    // k-slice kh -> hi chunk c = 2*kh + lhi (0..7), addr swizzled by row.
    const int r15 = l31 & 15;
    const int adrA = l31 * 256 + (((2 * kh + lhi) ^ r15) << 4);
    // B read base: bpack-linear LDS; slice kh -> sub = kh>>1, kq = (kh&1)*2+lhi
    const int offB0 = (kh >> 1) * 16384 + ((kh & 1) * 2 + lhi) * 4096
                    + (cgp * 64 + l31) * 16;          // ct=0, h=0
    const int offB1 = offB0 + 512;                    // ct=1 (+32 cols)

    #define COMPUTE(CUR) do {                                                 \
        const char* aB_ = ldsraw + (CUR) * 8192;                              \
        const char* bT_ = ldsB + (CUR) * 32768;                               \
        bf16x8_t ah  = *(const bf16x8_t*)(aB_ + adrA);                        \
        bf16x8_t al  = *(const bf16x8_t*)(aB_ + (adrA ^ 128));                \
        bf16x8_t bh0 = *(const bf16x8_t*)(bT_ + offB0);                       \
        bf16x8_t bh1 = *(const bf16x8_t*)(bT_ + offB1);                       \
        bf16x8_t bl0 = *(const bf16x8_t*)(bT_ + offB0 + 2048);                \
        bf16x8_t bl1 = *(const bf16x8_t*)(bT_ + offB1 + 2048);                \
        acc0 = __builtin_amdgcn_mfma_f32_32x32x16_bf16(ah, bh0, acc0, 0, 0, 0);\
        acc1 = __builtin_amdgcn_mfma_f32_32x32x16_bf16(ah, bh1, acc1, 0, 0, 0);\
        acc0 = __builtin_amdgcn_mfma_f32_32x32x16_bf16(al, bh0, acc0, 0, 0, 0);\
        acc1 = __builtin_amdgcn_mfma_f32_32x32x16_bf16(al, bh1, acc1, 0, 0, 0);\
        acc0 = __builtin_amdgcn_mfma_f32_32x32x16_bf16(ah, bl0, acc0, 0, 0, 0);\
        acc1 = __builtin_amdgcn_mfma_f32_32x32x16_bf16(ah, bl1, acc1, 0, 0, 0);\
    } while (0)

    // prologue: A(0) immediate, A(1) into rxB; B(0) DMA
    float4 rxA = *(const float4*)(sxa);
    STAGE_B(0, 0);
    WRITE_A(0, rxA);
    float4 rxB = *(const float4*)(sxa + 64);
    __syncthreads();

    for (int t = 0; t < NSTEP; t += 2) {
        // even step: consume buf0; rxB holds A(t+1)
        if (t + 2 < NSTEP) rxA = *(const float4*)(sxa + (t + 2) * 64);
        if (t + 1 < NSTEP) STAGE_B(1, t + 1);
        COMPUTE(0);
        if (t + 1 < NSTEP) WRITE_A(1, rxB);
        __syncthreads();
        // odd step: consume buf1; rxA holds A(t+2)
        if (t + 3 < NSTEP) rxB = *(const float4*)(sxa + (t + 3) * 64);
        if (t + 2 < NSTEP) STAGE_B(0, t + 2);
        COMPUTE(1);
        if (t + 2 < NSTEP) WRITE_A(0, rxA);
        __syncthreads();
    }
    #undef STAGE_B
    #undef WRITE_A
    #undef COMPUTE

    // per-(cgp,kh) 32x64 patch -> part[kh] (C/D map m74/m101:
    // col = lane&31, row = (reg&3) + 8*(reg>>2) + 4*(lane>>5))
    float (*part)[32][132] = (float (*)[32][132])ldsraw;   // [4][32][132] = 67584 B
    #pragma unroll
    for (int r = 0; r < 16; ++r) {
        int row = (r & 3) + 8 * (r >> 2) + 4 * lhi;
        part[kh][row][cgp * 64 + l31]      = acc0[r];
        part[kh][row][cgp * 64 + 32 + l31] = acc1[r];
    }
    __syncthreads();

    // ---- routing epilogue (verified r1-r13): 8 waves x 4 tokens ----
    const float br = b_route[lane];
    const float bnv = b_noise[lane];
    float ps_l = 0.f, fr_l = 0.f, l2_l = 0.f;

    for (int tt = 0; tt < 4; ++tt) {
        const int tok = wid * 4 + tt;
        const int gt  = bm + tok;
        float lr = part[0][tok][lane] + part[1][tok][lane]
                 + part[2][tok][lane] + part[3][tok][lane] + br;
        float ln = part[0][tok][64 + lane] + part[1][tok][64 + lane]
                 + part[2][tok][64 + lane] + part[3][tok][64 + lane] + bnv;
        float nz = noise[(size_t)gt * NX + lane];
        float sp = fmaxf(ln, 0.f) + log1pf(expf(-fabsf(ln)));   // softplus
        float v  = lr + nz * sp;                                 // noisy logit

        // top-9 iterative wave argmax (ties -> lower index)
        float vv = v;
        float tv[9]; int ti[9];
        #pragma unroll
        for (int s = 0; s < 9; ++s) {
            float mv = vv; int mi = lane;
            #pragma unroll
            for (int off = 32; off > 0; off >>= 1) {
                float ov = __shfl_xor(mv, off);
                int   oi = __shfl_xor(mi, off);
                if (ov > mv || (ov == mv && oi < mi)) { mv = ov; mi = oi; }
            }
            tv[s] = mv; ti[s] = mi;
            if (lane == mi) vv = neginf();
        }

        float ming = 1e30f;
        #pragma unroll
        for (int s = 0; s < 8; ++s) ming = fminf(ming, tv[s] - tv[s + 1]);
        if (lane == 0 && ming < DELTA_BF16) {
            int p = atomicAdd(flag_cnt, 1);
            if (p < MAXFLAG) flag_list[p] = gt;
        }

        const float m0 = tv[0];
        float e8[8], s8 = 0.f;
        #pragma unroll
        for (int s = 0; s < 8; ++s) { e8[s] = expf(tv[s] - m0); s8 += e8[s]; }
        float r = 0.f;
        #pragma unroll
        for (int s = 0; s < 8; ++s) if (ti[s] == lane) r = e8[s] / s8;
        out[(size_t)gt * NX + lane] = r;
        if (lane < TK) out[TI_OFF + (size_t)gt * TK + lane] = (float)ti[lane];

        float p = expf(v - m0);
        float s64 = p;
        #pragma unroll
        for (int off = 32; off > 0; off >>= 1) s64 += __shfl_xor(s64, off);
        ps_l += p / s64;
        if (lane == 0) { float lse = m0 + logf(s64); l2_l += lse * lse; }

        unsigned tm8 = 0;
        #pragma unroll
        for (int s = 0; s < 8; ++s) if (ti[s] < TK) tm8 |= (1u << ti[s]);
        #pragma unroll
        for (int s = 0; s < 8; ++s)
            if (ti[s] == lane && ((tm8 >> s) & 1u)) fr_l += 1.f;
    }

    // ---- privatized per-block stats (no global atomics) ----
    float* sps = (float*)(ldsraw + 69632);          // [8][64]
    float* sfr = (float*)(ldsraw + 69632 + 2048);   // [8][64]
    float* sl2 = (float*)(ldsraw + 69632 + 4096);   // [8]
    sps[wid * 64 + lane] = ps_l;
    sfr[wid * 64 + lane] = fr_l;
    if (lane == 0) sl2[wid] = l2_l;
    __syncthreads();
    if (wid == 0) {
        float a = 0.f, b = 0.f;
        #pragma unroll
        for (int w = 0; w < 8; ++w) {
            a += sps[w * 64 + lane];
            b += sfr[w * 64 + lane];
        }
        ps_blk[(size_t)blockIdx.x * 64 + lane] = a;
        fr_blk[(size_t)blockIdx.x * 64 + lane] = b;
        if (lane == 0) {
            float z = 0.f;
            #pragma unroll
            for (int w = 0; w < 8; ++w) z += sl2[w];
            lse2_blk[blockIdx.x] = z;
        }
    }
}

// ---------------------------------------------------------------------------
// Fallback fp32-VALU fused kernel (round-1 verified) for small ws_size.
// ---------------------------------------------------------------------------
#define FBM 64
#define FBN 128
#define FBK 32
#define XPITCH (FBM + 4)
__global__ __launch_bounds__(256) void fused_router_kernel(
    const float* __restrict__ x,
    const float* __restrict__ w_route, const float* __restrict__ b_route,
    const float* __restrict__ w_noise, const float* __restrict__ b_noise,
    const float* __restrict__ noise,
    float* __restrict__ out,
    float* __restrict__ ps_acc, float* __restrict__ fr_acc,
    float* __restrict__ lse2_acc,
    int* __restrict__ flag_cnt, int* __restrict__ flag_list)
{
    __shared__ float smem[FBM * FBN];
    float* xs  = smem;
    float* wst = smem + FBK * XPITCH;
    const int tid = threadIdx.x;
    const int block_m = blockIdx.x * FBM;
    const int row0 = (tid >> 5) * 8;
    const int col0 = (tid & 31) * 4;
    float acc[8][4];
    #pragma unroll
    for (int i = 0; i < 8; ++i)
        #pragma unroll
        for (int j = 0; j < 4; ++j) acc[i][j] = 0.f;
    float4 px[2], pw[4];
    {
        #pragma unroll
        for (int s = 0; s < 2; ++s) {
            int f = tid + s * 256, r = f >> 3, kqv = f & 7;
            px[s] = *reinterpret_cast<const float4*>(x + (size_t)(block_m + r) * NE + kqv * 4);
        }
        #pragma unroll
        for (int s = 0; s < 4; ++s) {
            int f = tid + s * 256, kk = f >> 5, c4 = (f & 31) * 4;
            const float* src = (c4 < NX) ? (w_route + (size_t)kk * NX + c4)
                                         : (w_noise + (size_t)kk * NX + (c4 - NX));
            pw[s] = *reinterpret_cast<const float4*>(src);
        }
    }
    for (int t = 0; t < NE / FBK; ++t) {
        __syncthreads();
        #pragma unroll
        for (int s = 0; s < 2; ++s) {
            int f = tid + s * 256, r = f >> 3, kqv = f & 7;
            xs[(kqv * 4 + 0) * XPITCH + r] = px[s].x;
            xs[(kqv * 4 + 1) * XPITCH + r] = px[s].y;
            xs[(kqv * 4 + 2) * XPITCH + r] = px[s].z;
            xs[(kqv * 4 + 3) * XPITCH + r] = px[s].w;
        }
        #pragma unroll
        for (int s = 0; s < 4; ++s) {
            int f = tid + s * 256, kk = f >> 5, c4 = (f & 31) * 4;
            *reinterpret_cast<float4*>(&wst[kk * FBN + c4]) = pw[s];
        }
        __syncthreads();
        if (t + 1 < NE / FBK) {
            const int k0 = (t + 1) * FBK;
            #pragma unroll
            for (int s = 0; s < 2; ++s) {
                int f = tid + s * 256, r = f >> 3, kqv = f & 7;
                px[s] = *reinterpret_cast<const float4*>(x + (size_t)(block_m + r) * NE + k0 + kqv * 4);
            }
            #pragma unroll
            for (int s = 0; s < 4; ++s) {
                int f = tid + s * 256, kk = f >> 5, c4 = (f & 31) * 4;
                const float* src = (c4 < NX) ? (w_route + (size_t)kk * NX + c4)
                                             : (w_noise + (size_t)(k0 + kk) * NX + (c4 - NX));
                if (c4 < NX) src = w_route + (size_t)(k0 + kk) * NX + c4;
                pw[s] = *reinterpret_cast<const float4*>(src);
            }
        }
        #pragma unroll
        for (int k = 0; k < FBK; ++k) {
            float4 xa = *reinterpret_cast<const float4*>(&xs[k * XPITCH + row0]);
            float4 xb = *reinterpret_cast<const float4*>(&xs[k * XPITCH + row0 + 4]);
            float4 wv = *reinterpret_cast<const float4*>(&wst[k * FBN + col0]);
            float xf[8] = {xa.x, xa.y, xa.z, xa.w, xb.x, xb.y, xb.z, xb.w};
            float wf[4] = {wv.x, wv.y, wv.z, wv.w};
            #pragma unroll
            for (int i = 0; i < 8; ++i)
                #pragma unroll
                for (int j = 0; j < 4; ++j)
                    acc[i][j] = fmaf(xf[i], wf[j], acc[i][j]);
        }
    }
    __syncthreads();
    #pragma unroll
    for (int i = 0; i < 8; ++i) {
        float4 v = make_float4(acc[i][0], acc[i][1], acc[i][2], acc[i][3]);
        *reinterpret_cast<float4*>(&smem[(row0 + i) * FBN + col0]) = v;
    }
    __syncthreads();
    const int wave = tid >> 6;
    const int lane = tid & 63;
    const float br = b_route[lane];
    const float bnv = b_noise[lane];
    float ps_l = 0.f, fr_l = 0.f, l2_l = 0.f;
    for (int tt = 0; tt < FBM / 4; ++tt) {
        const int tok = wave * (FBM / 4) + tt;
        const int gt  = block_m + tok;
        float lr = smem[tok * FBN + lane] + br;
        float ln = smem[tok * FBN + NX + lane] + bnv;
        float nz = noise[(size_t)gt * NX + lane];
        float sp = fmaxf(ln, 0.f) + log1pf(expf(-fabsf(ln)));
        float v  = lr + nz * sp;
        float vv = v;
        float tv[9]; int ti[9];
        #pragma unroll
        for (int s = 0; s < 9; ++s) {
            float mv = vv; int mi = lane;
            #pragma unroll
            for (int off = 32; off > 0; off >>= 1) {
                float ov = __shfl_xor(mv, off);
                int   oi = __shfl_xor(mi, off);
                if (ov > mv || (ov == mv && oi < mi)) { mv = ov; mi = oi; }
            }
            tv[s] = mv; ti[s] = mi;
            if (lane == mi) vv = neginf();
        }
        float ming = 1e30f;
        #pragma unroll
        for (int s = 0; s < 8; ++s) ming = fminf(ming, tv[s] - tv[s + 1]);
        if (lane == 0 && ming < DELTA_FP32) {
            int p = atomicAdd(flag_cnt, 1);
            if (p < MAXFLAG) flag_list[p] = gt;
        }
        const float m0 = tv[0];
        float e8[8], s8 = 0.f;
        #pragma unroll
        for (int s = 0; s < 8; ++s) { e8[s] = expf(tv[s] - m0); s8 += e8[s]; }
        float r = 0.f;
        #pragma unroll
        for (int s = 0; s < 8; ++s) if (ti[s] == lane) r = e8[s] / s8;
        out[(size_t)gt * NX + lane] = r;
        if (lane < TK) out[TI_OFF + (size_t)gt * TK + lane] = (float)ti[lane];
        float p = expf(v - m0);
        float s64 = p;
        #pragma unroll
        for (int off = 32; off > 0; off >>= 1) s64 += __shfl_xor(s64, off);
        ps_l += p / s64;
        if (lane == 0) { float lse = m0 + logf(s64); l2_l += lse * lse; }
        unsigned tm8 = 0;
        #pragma unroll
        for (int s = 0; s < 8; ++s) if (ti[s] < TK) tm8 |= (1u << ti[s]);
        #pragma unroll
        for (int s = 0; s < 8; ++s)
            if (ti[s] == lane && ((tm8 >> s) & 1u)) fr_l += 1.f;
    }
    atomicAdd(&ps_acc[lane], ps_l);
    atomicAdd(&fr_acc[lane], fr_l);
    if (lane == 0) atomicAdd(lse2_acc, l2_l);
}

// ---------------------------------------------------------------------------
// fp64 repair of near-tie tokens (verified r3-r13)
// ---------------------------------------------------------------------------
__global__ __launch_bounds__(256) void refine_kernel(
    const float* __restrict__ x, const float* __restrict__ w_route,
    const float* __restrict__ b_route, const float* __restrict__ w_noise,
    const float* __restrict__ b_noise, const float* __restrict__ noise,
    float* __restrict__ out, const int* __restrict__ flag_cnt,
    const int* __restrict__ flag_list)
{
    __shared__ double red[8][64];
    const int tid = threadIdx.x;
    const int lane = tid & 63, wq = tid >> 6;
    int nf = *flag_cnt; if (nf > MAXFLAG) nf = MAXFLAG;
    for (int fi = blockIdx.x; fi < nf; fi += gridDim.x) {
        const int gt = flag_list[fi];
        const float* xr = x + (size_t)gt * NE + wq * 1024;
        const float* wr = w_route + (size_t)wq * 1024 * NX;
        const float* wn = w_noise + (size_t)wq * 1024 * NX;
        double ar0 = 0, ar1 = 0, an0 = 0, an1 = 0;
        for (int k = 0; k < 1024; k += 2) {
            double x0 = xr[k], x1 = xr[k + 1];
            ar0 += x0 * (double)wr[(size_t)k * NX + lane];
            ar1 += x1 * (double)wr[(size_t)(k + 1) * NX + lane];
            an0 += x0 * (double)wn[(size_t)k * NX + lane];
            an1 += x1 * (double)wn[(size_t)(k + 1) * NX + lane];
        }
        red[wq * 2][lane]     = ar0 + ar1;
        red[wq * 2 + 1][lane] = an0 + an1;
        __syncthreads();
        if (tid < 64) {
            double lr = red[0][lane] + red[2][lane] + red[4][lane] + red[6][lane]
                      + (double)b_route[lane];
            double ln = red[1][lane] + red[3][lane] + red[5][lane] + red[7][lane]
                      + (double)b_noise[lane];
            double nz = (double)noise[(size_t)gt * NX + lane];
            double sp = (ln > 0.0) ? (ln + log1p(exp(-ln))) : log1p(exp(ln));
            double v  = lr + nz * sp;
            double vv = v;
            double tv[8]; int ti[8];
            #pragma unroll
            for (int s = 0; s < 8; ++s) {
                double mv = vv; int mi = lane;
                #pragma unroll
                for (int off = 32; off > 0; off >>= 1) {
                    double ov = __shfl_xor(mv, off);
                    int    oi = __shfl_xor(mi, off);
                    if (ov > mv || (ov == mv && oi < mi)) { mv = ov; mi = oi; }
                }
                tv[s] = mv; ti[s] = mi;
                if (lane == mi) vv = -1.0e300;
            }
            double m0 = tv[0], s8 = 0.0, e8[8];
            #pragma unroll
            for (int s = 0; s < 8; ++s) { e8[s] = exp(tv[s] - m0); s8 += e8[s]; }
            float r = 0.f;
            #pragma unroll
            for (int s = 0; s < 8; ++s) if (ti[s] == lane) r = (float)(e8[s] / s8);
            out[(size_t)gt * NX + lane] = r;
            if (lane < TK) out[TI_OFF + (size_t)gt * TK + lane] = (float)ti[lane];
        }
        __syncthreads();
    }
}

// ---------------------------------------------------------------------------
// finalize: deterministic reduce of per-block stats, compute aux loss
// ---------------------------------------------------------------------------
__global__ __launch_bounds__(512) void finalize_kernel(
    const float* __restrict__ ps_blk, const float* __restrict__ fr_blk,
    const float* __restrict__ lse2_blk, float* __restrict__ out)
{
    __shared__ float sps[8][64], sfr[8][64], sl2[512];
    const int t = threadIdx.x;
    const int e = t & 63, g = t >> 6;
    float a = 0.f, b = 0.f;
    for (int blk = g; blk < NBLK; blk += 8) {
        a += ps_blk[(size_t)blk * 64 + e];
        b += fr_blk[(size_t)blk * 64 + e];
    }
    sps[g][e] = a;
    sfr[g][e] = b;
    sl2[t] = lse2_blk[t];
    __syncthreads();
    if (t < 64) {
        float p = 0.f, f = 0.f;
        #pragma unroll
        for (int gg = 0; gg < 8; ++gg) { p += sps[gg][t]; f += sfr[gg][t]; }
        float z = 0.f;
        #pragma unroll
        for (int i = 0; i < 8; ++i) z += sl2[t * 8 + i];
        float sp = p, sf = f, sz = z;
        #pragma unroll
        for (int off = 32; off > 0; off >>= 1) {
            sp += __shfl_xor(sp, off);
            sf += __shfl_xor(sf, off);
            sz += __shfl_xor(sz, off);
        }
        float d = (p / fmaxf(sp, 1e-12f)) * (f / fmaxf(sf, 1e-12f));
        #pragma unroll
        for (int off = 32; off > 0; off >>= 1) d += __shfl_xor(d, off);
        if (t == 0)
            out[AUX_IDX] = 64.f * d + 0.1f * (sz / (float)NT);
    }
}

// ---------------------------------------------------------------------------
extern "C" void kernel_launch(void* const* d_in, const int* in_sizes, int n_in,
                              void* d_out, int out_size, void* d_ws, size_t ws_size,
                              hipStream_t stream) {
    const float* x       = (const float*)d_in[0];
    const float* w_route = (const float*)d_in[1];
    const float* b_route = (const float*)d_in[2];
    const float* w_noise = (const float*)d_in[3];
    const float* b_noise = (const float*)d_in[4];
    const float* noise   = (const float*)d_in[5];
    float* out = (float*)d_out;

    float* wsf = (float*)d_ws;
    int* flag_cnt  = (int*)wsf;
    int* flag_list = (int*)(wsf + 1);
    float* ps_blk   = wsf + PSB_IDX;
    float* fr_blk   = wsf + FRB_IDX;
    float* lse2_blk = wsf + L2B_IDX;

    // zero flag region (cnt + list)
    hipMemsetAsync(d_ws, 0, (size_t)(1 + MAXFLAG) * sizeof(int), stream);

    if (ws_size >= WS_NEED) {
        unsigned short* bpack = (unsigned short*)((char*)d_ws + BPACK_OFF);
        prep_w_kernel<<<128, 512, 0, stream>>>(w_route, w_noise, bpack);
        fused32_kernel<<<NBLK, 512, 0, stream>>>(
            x, bpack, b_route, b_noise, noise, out,
            ps_blk, fr_blk, lse2_blk, flag_cnt, flag_list);
    } else {
        // fallback: zero whole stats region, atomic-accumulate into row 0
        hipMemsetAsync(ps_blk, 0,
                       (size_t)(WS_FLOATS - PSB_IDX) * sizeof(float), stream);
        fused_router_kernel<<<NT / FBM, 256, 0, stream>>>(
            x, w_route, b_route, w_noise, b_noise, noise, out,
            ps_blk, fr_blk, lse2_blk, flag_cnt, flag_list);
    }

    refine_kernel<<<1024, 256, 0, stream>>>(
        x, w_route, b_route, w_noise, b_noise, noise, out, flag_cnt, flag_list);

    finalize_kernel<<<1, 512, 0, stream>>>(ps_blk, fr_blk, lse2_blk, out);
}

// Round 16
// 193.137 us; speedup vs baseline: 1.0482x; 1.0351x over previous
//
#include <hip/hip_runtime.h>
#include <math.h>

#define NT 16384     // tokens
#define NE 4096      // embed
#define NX 64        // experts
#define TK 8         // top-k

#define BM 32
#define NBLK (NT / BM)        // 512 blocks
#define NSTEP 64              // K-steps of BK=64

#define RO_SIZE (NT * NX)
#define TI_OFF  RO_SIZE
#define AUX_IDX (RO_SIZE + NT * TK)

#define MAXFLAG 8192
// ws float layout: [0]=flag_cnt, [1..1+MAXFLAG)=flag_list,
// ps_blk[512][64], fr_blk[512][64], lse2_blk[512], then bpack (bytes)
#define PSB_IDX 8256
#define FRB_IDX (PSB_IDX + NBLK * 64)
#define L2B_IDX (FRB_IDX + NBLK * 64)
#define WS_FLOATS (L2B_IDX + NBLK)
#define BPACK_OFF (((WS_FLOATS * 4) + 255) & ~255)
#define BPACK_USHORTS (128 * 4 * 2 * 128 * 8)   // 1M ushorts (2MB)
#define WS_NEED ((size_t)BPACK_OFF + (size_t)BPACK_USHORTS * 2)

#define DELTA_FP32 5e-5f
#define DELTA_BF16 2.5e-4f   // bf16x3 sigma ~1.5-2e-5, >12-sigma margin (verified r2-r15)

typedef __attribute__((ext_vector_type(8))) short bf16x8_t;
typedef __attribute__((ext_vector_type(4))) float f32x4_t;
typedef __attribute__((ext_vector_type(16))) float f32x16_t;

__device__ __forceinline__ float neginf() { return __int_as_float(0xff800000); }

__device__ __forceinline__ unsigned short bf16_trunc(float f) {
    return (unsigned short)(__float_as_uint(f) >> 16);
}
__device__ __forceinline__ unsigned short bf16_rtn(float f) {
    unsigned u = __float_as_uint(f);
    unsigned r = u + 0x7fffu + ((u >> 16) & 1u);
    return (unsigned short)(r >> 16);
}
__device__ __forceinline__ float bf16_to_f(unsigned short h) {
    return __uint_as_float(((unsigned)h) << 16);
}

// cheap 4-float split: hi = trunc bf16 (v_perm pack), lo = trunc bf16 of (f - hi)
__device__ __forceinline__ void split4(const float4& f,
                                       unsigned& h0, unsigned& h1,
                                       unsigned& l0, unsigned& l1) {
    unsigned u0 = __float_as_uint(f.x), u1 = __float_as_uint(f.y);
    unsigned u2 = __float_as_uint(f.z), u3 = __float_as_uint(f.w);
    h0 = __builtin_amdgcn_perm(u1, u0, 0x07060302u);   // {bf16(f.x), bf16(f.y)}
    h1 = __builtin_amdgcn_perm(u3, u2, 0x07060302u);
    float g0 = f.x - __uint_as_float(u0 & 0xffff0000u);
    float g1 = f.y - __uint_as_float(u1 & 0xffff0000u);
    float g2 = f.z - __uint_as_float(u2 & 0xffff0000u);
    float g3 = f.w - __uint_as_float(u3 & 0xffff0000u);
    l0 = __builtin_amdgcn_perm(__float_as_uint(g1), __float_as_uint(g0), 0x07060302u);
    l1 = __builtin_amdgcn_perm(__float_as_uint(g3), __float_as_uint(g2), 0x07060302u);
}

// async 16B global->LDS DMA (LDS dest = wave-uniform base + lane*16)
#define GLOAD16(GP, LP) __builtin_amdgcn_global_load_lds(                     \
    (const __attribute__((address_space(1))) void*)(GP),                      \
    (__attribute__((address_space(3))) void*)(LP), 16, 0, 0)

// ---------------------------------------------------------------------------
// prep: pack w_route|w_noise into fragment-major hi/lo bf16 (verified r4-r15):
// chunk(kt,kq,h,col) = ((kt*4+kq)*2 + h)*128 + col, 8 ushorts per chunk.
// ---------------------------------------------------------------------------
__global__ __launch_bounds__(512) void prep_w_kernel(
    const float* __restrict__ w_route, const float* __restrict__ w_noise,
    unsigned short* __restrict__ bp)
{
    const int kt = blockIdx.x;
    const int t = threadIdx.x;
    const int col = t & 127;
    const int kq = t >> 7;
    const float* src = (col < NX) ? (w_route + col) : (w_noise + (col - NX));
    const int kbase = kt * 32 + kq * 8;
    bf16x8_t h8, l8;
    #pragma unroll
    for (int i = 0; i < 8; ++i) {
        float v = src[(size_t)(kbase + i) * NX];
        unsigned short hh = bf16_trunc(v);
        h8[i] = (short)hh;
        l8[i] = (short)bf16_rtn(v - bf16_to_f(hh));
    }
    unsigned short* base = bp + ((size_t)((kt * 4 + kq) * 2) * 128 + col) * 8;
    *(bf16x8_t*)base = h8;                 // h = 0
    *(bf16x8_t*)(base + 128 * 8) = l8;     // h = 1
}

// ---------------------------------------------------------------------------
// Fused GEMM + routing, 32x32x16 MFMA, 1024 threads = 16 waves
// (cgq{4 col-tiles} x kh{4 k-slices}), 2 blocks/CU -> 32 waves/CU (100% occ).
// A: reg-staged by tid<512 (float4 -> split4 -> ds_write hi/lo, swizzled),
// dbuf 16KB, rx 2-deep. B: global_load_lds DMA dbuf 64KB (all 1024 threads).
// Per wave/step: 2 A ds_reads, 2 B ds_reads, 3 MFMA.
// ---------------------------------------------------------------------------
__global__ __launch_bounds__(1024, 8) void fused32_kernel(
    const float* __restrict__ x,
    const unsigned short* __restrict__ bp,
    const float* __restrict__ b_route, const float* __restrict__ b_noise,
    const float* __restrict__ noise,
    float* __restrict__ out,
    float* __restrict__ ps_blk, float* __restrict__ fr_blk,
    float* __restrict__ lse2_blk,
    int* __restrict__ flag_cnt, int* __restrict__ flag_list)
{
    __shared__ __align__(16) char ldsraw[81920];   // A bf16 dbuf 16KB | B dbuf 64KB

    const int tid = threadIdx.x;
    const int wid = tid >> 6;          // 0..15
    const int lane = tid & 63;
    const int l31 = lane & 31;
    const int lhi = lane >> 5;         // k-octet selector within a 16-k slice
    const int cgq = wid & 3;           // col-tile (32 cols each)
    const int kh = wid >> 2;           // k-slice (0..3): 16-k slice per step
    const int bm = blockIdx.x * BM;
    const bool stager = (tid < 512);

    // ---- A staging map (verified r11-r15), active for tid<512 ----
    const int srow = (tid >> 4) & 31;   // 0..31
    const int sq = tid & 15;            // k = sq*4 .. +3
    const int skc = sq >> 1;
    const int shalf = sq & 1;
    const int srl = srow & 15;
    // A layout per buf: [row32][16 chunks x 16B]; hi chunk c=kc, lo c=8+kc;
    // stored at c ^ (row&15); lo = hi offset ^ 128.
    const int offA = srow * 256 + ((skc ^ srl) << 4) + shalf * 8;
    const float* sxa = x + (size_t)(bm + srow) * NE + sq * 4;

    char* ldsB = ldsraw + 16384;
    char* dB = ldsB + tid * 16;

    // B staging: 1024 threads x 2 GLOAD16 = 32KB per step
    #define STAGE_B(BUF, ST) do {                                             \
        const unsigned short* sB_ = bp + (size_t)(ST) * 16384 + tid * 8;      \
        char* dB_ = dB + (BUF) * 32768;                                       \
        GLOAD16(sB_,         dB_);                                            \
        GLOAD16(sB_ + 8192,  dB_ + 16384);                                    \
    } while (0)

    #define WRITE_A(BUF, RX) do {                                             \
        if (stager) {                                                         \
            unsigned h0_, h1_, l0_, l1_;                                      \
            split4(RX, h0_, h1_, l0_, l1_);                                   \
            const int ob_ = (BUF) * 8192;                                     \
            *(int2*)(ldsraw + ob_ + offA)         = make_int2((int)h0_, (int)h1_);\
            *(int2*)(ldsraw + ob_ + (offA ^ 128)) = make_int2((int)l0_, (int)l1_);\
        }                                                                     \
    } while (0)

    f32x16_t acc;
    #pragma unroll
    for (int i = 0; i < 16; ++i) acc[i] = 0.f;

    // A read offset (32x32x16 frag: lane=row+32*(k>>3), 8 contiguous k):
    // k-slice kh -> hi chunk c = 2*kh + lhi (0..7), addr swizzled by row.
    const int r15 = l31 & 15;
    const int adrA = l31 * 256 + (((2 * kh + lhi) ^ r15) << 4);
    // B read base: bpack-linear LDS; slice kh -> sub = kh>>1, kq = (kh&1)*2+lhi
    const int offB = (kh >> 1) * 16384 + ((kh & 1) * 2 + lhi) * 4096
                   + (cgq * 32 + l31) * 16;           // h=0; +2048 for lo

    #define COMPUTE(CUR) do {                                                 \
        const char* aB_ = ldsraw + (CUR) * 8192;                              \
        const char* bT_ = ldsB + (CUR) * 32768;                               \
        bf16x8_t ah = *(const bf16x8_t*)(aB_ + adrA);                         \
        bf16x8_t al = *(const bf16x8_t*)(aB_ + (adrA ^ 128));                 \
        bf16x8_t bh = *(const bf16x8_t*)(bT_ + offB);                         \
        bf16x8_t bl = *(const bf16x8_t*)(bT_ + offB + 2048);                  \
        acc = __builtin_amdgcn_mfma_f32_32x32x16_bf16(ah, bh, acc, 0, 0, 0);  \
        acc = __builtin_amdgcn_mfma_f32_32x32x16_bf16(al, bh, acc, 0, 0, 0);  \
        acc = __builtin_amdgcn_mfma_f32_32x32x16_bf16(ah, bl, acc, 0, 0, 0);  \
    } while (0)

    // prologue: A(0) immediate, A(1) into rxB; B(0) DMA
    float4 rxA, rxB;
    if (stager) rxA = *(const float4*)(sxa);
    STAGE_B(0, 0);
    WRITE_A(0, rxA);
    if (stager) rxB = *(const float4*)(sxa + 64);
    __syncthreads();

    for (int t = 0; t < NSTEP; t += 2) {
        // even step: consume buf0; rxB holds A(t+1)
        if (stager && t + 2 < NSTEP) rxA = *(const float4*)(sxa + (t + 2) * 64);
        if (t + 1 < NSTEP) STAGE_B(1, t + 1);
        COMPUTE(0);
        if (t + 1 < NSTEP) WRITE_A(1, rxB);
        __syncthreads();
        // odd step: consume buf1; rxA holds A(t+2)
        if (stager && t + 3 < NSTEP) rxB = *(const float4*)(sxa + (t + 3) * 64);
        if (t + 2 < NSTEP) STAGE_B(0, t + 2);
        COMPUTE(1);
        if (t + 2 < NSTEP) WRITE_A(0, rxA);
        __syncthreads();
    }
    #undef STAGE_B
    #undef WRITE_A
    #undef COMPUTE

    // per-(cgq,kh) 32x32 patch -> part[kh] (C/D map m74/m101:
    // col = lane&31, row = (reg&3) + 8*(reg>>2) + 4*(lane>>5))
    float (*part)[32][132] = (float (*)[32][132])ldsraw;   // [4][32][132] = 67584 B
    #pragma unroll
    for (int r = 0; r < 16; ++r) {
        int row = (r & 3) + 8 * (r >> 2) + 4 * lhi;
        part[kh][row][cgq * 32 + l31] = acc[r];
    }
    __syncthreads();

    // ---- routing epilogue (verified r1-r15): 16 waves x 2 tokens ----
    const float br = b_route[lane];
    const float bnv = b_noise[lane];
    float ps_l = 0.f, fr_l = 0.f, l2_l = 0.f;

    for (int tt = 0; tt < 2; ++tt) {
        const int tok = wid * 2 + tt;
        const int gt  = bm + tok;
        float lr = part[0][tok][lane] + part[1][tok][lane]
                 + part[2][tok][lane] + part[3][tok][lane] + br;
        float ln = part[0][tok][64 + lane] + part[1][tok][64 + lane]
                 + part[2][tok][64 + lane] + part[3][tok][64 + lane] + bnv;
        float nz = noise[(size_t)gt * NX + lane];
        float sp = fmaxf(ln, 0.f) + log1pf(expf(-fabsf(ln)));   // softplus
        float v  = lr + nz * sp;                                 // noisy logit

        // top-9 iterative wave argmax (ties -> lower index)
        float vv = v;
        float tv[9]; int ti[9];
        #pragma unroll
        for (int s = 0; s < 9; ++s) {
            float mv = vv; int mi = lane;
            #pragma unroll
            for (int off = 32; off > 0; off >>= 1) {
                float ov = __shfl_xor(mv, off);
                int   oi = __shfl_xor(mi, off);
                if (ov > mv || (ov == mv && oi < mi)) { mv = ov; mi = oi; }
            }
            tv[s] = mv; ti[s] = mi;
            if (lane == mi) vv = neginf();
        }

        float ming = 1e30f;
        #pragma unroll
        for (int s = 0; s < 8; ++s) ming = fminf(ming, tv[s] - tv[s + 1]);
        if (lane == 0 && ming < DELTA_BF16) {
            int p = atomicAdd(flag_cnt, 1);
            if (p < MAXFLAG) flag_list[p] = gt;
        }

        const float m0 = tv[0];
        float e8[8], s8 = 0.f;
        #pragma unroll
        for (int s = 0; s < 8; ++s) { e8[s] = expf(tv[s] - m0); s8 += e8[s]; }
        float r = 0.f;
        #pragma unroll
        for (int s = 0; s < 8; ++s) if (ti[s] == lane) r = e8[s] / s8;
        out[(size_t)gt * NX + lane] = r;
        if (lane < TK) out[TI_OFF + (size_t)gt * TK + lane] = (float)ti[lane];

        float p = expf(v - m0);
        float s64 = p;
        #pragma unroll
        for (int off = 32; off > 0; off >>= 1) s64 += __shfl_xor(s64, off);
        ps_l += p / s64;
        if (lane == 0) { float lse = m0 + logf(s64); l2_l += lse * lse; }

        unsigned tm8 = 0;
        #pragma unroll
        for (int s = 0; s < 8; ++s) if (ti[s] < TK) tm8 |= (1u << ti[s]);
        #pragma unroll
        for (int s = 0; s < 8; ++s)
            if (ti[s] == lane && ((tm8 >> s) & 1u)) fr_l += 1.f;
    }

    // ---- privatized per-block stats (no global atomics) ----
    float* sps = (float*)(ldsraw + 69632);          // [16][64]
    float* sfr = (float*)(ldsraw + 69632 + 4096);   // [16][64]
    float* sl2 = (float*)(ldsraw + 69632 + 8192);   // [16]
    sps[wid * 64 + lane] = ps_l;
    sfr[wid * 64 + lane] = fr_l;
    if (lane == 0) sl2[wid] = l2_l;
    __syncthreads();
    if (wid == 0) {
        float a = 0.f, b = 0.f;
        #pragma unroll
        for (int w = 0; w < 16; ++w) {
            a += sps[w * 64 + lane];
            b += sfr[w * 64 + lane];
        }
        ps_blk[(size_t)blockIdx.x * 64 + lane] = a;
        fr_blk[(size_t)blockIdx.x * 64 + lane] = b;
        if (lane == 0) {
            float z = 0.f;
            #pragma unroll
            for (int w = 0; w < 16; ++w) z += sl2[w];
            lse2_blk[blockIdx.x] = z;
        }
    }
}

// ---------------------------------------------------------------------------
// Fallback fp32-VALU fused kernel (round-1 verified) for small ws_size.
// ---------------------------------------------------------------------------
#define FBM 64
#define FBN 128
#define FBK 32
#define XPITCH (FBM + 4)
__global__ __launch_bounds__(256) void fused_router_kernel(
    const float* __restrict__ x,
    const float* __restrict__ w_route, const float* __restrict__ b_route,
    const float* __restrict__ w_noise, const float* __restrict__ b_noise,
    const float* __restrict__ noise,
    float* __restrict__ out,
    float* __restrict__ ps_acc, float* __restrict__ fr_acc,
    float* __restrict__ lse2_acc,
    int* __restrict__ flag_cnt, int* __restrict__ flag_list)
{
    __shared__ float smem[FBM * FBN];
    float* xs  = smem;
    float* wst = smem + FBK * XPITCH;
    const int tid = threadIdx.x;
    const int block_m = blockIdx.x * FBM;
    const int row0 = (tid >> 5) * 8;
    const int col0 = (tid & 31) * 4;
    float acc[8][4];
    #pragma unroll
    for (int i = 0; i < 8; ++i)
        #pragma unroll
        for (int j = 0; j < 4; ++j) acc[i][j] = 0.f;
    float4 px[2], pw[4];
    {
        #pragma unroll
        for (int s = 0; s < 2; ++s) {
            int f = tid + s * 256, r = f >> 3, kqv = f & 7;
            px[s] = *reinterpret_cast<const float4*>(x + (size_t)(block_m + r) * NE + kqv * 4);
        }
        #pragma unroll
        for (int s = 0; s < 4; ++s) {
            int f = tid + s * 256, kk = f >> 5, c4 = (f & 31) * 4;
            const float* src = (c4 < NX) ? (w_route + (size_t)kk * NX + c4)
                                         : (w_noise + (size_t)kk * NX + (c4 - NX));
            pw[s] = *reinterpret_cast<const float4*>(src);
        }
    }
    for (int t = 0; t < NE / FBK; ++t) {
        __syncthreads();
        #pragma unroll
        for (int s = 0; s < 2; ++s) {
            int f = tid + s * 256, r = f >> 3, kqv = f & 7;
            xs[(kqv * 4 + 0) * XPITCH + r] = px[s].x;
            xs[(kqv * 4 + 1) * XPITCH + r] = px[s].y;
            xs[(kqv * 4 + 2) * XPITCH + r] = px[s].z;
            xs[(kqv * 4 + 3) * XPITCH + r] = px[s].w;
        }
        #pragma unroll
        for (int s = 0; s < 4; ++s) {
            int f = tid + s * 256, kk = f >> 5, c4 = (f & 31) * 4;
            *reinterpret_cast<float4*>(&wst[kk * FBN + c4]) = pw[s];
        }
        __syncthreads();
        if (t + 1 < NE / FBK) {
            const int k0 = (t + 1) * FBK;
            #pragma unroll
            for (int s = 0; s < 2; ++s) {
                int f = tid + s * 256, r = f >> 3, kqv = f & 7;
                px[s] = *reinterpret_cast<const float4*>(x + (size_t)(block_m + r) * NE + k0 + kqv * 4);
            }
            #pragma unroll
            for (int s = 0; s < 4; ++s) {
                int f = tid + s * 256, kk = f >> 5, c4 = (f & 31) * 4;
                const float* src = (c4 < NX) ? (w_route + (size_t)(k0 + kk) * NX + c4)
                                             : (w_noise + (size_t)(k0 + kk) * NX + (c4 - NX));
                pw[s] = *reinterpret_cast<const float4*>(src);
            }
        }
        #pragma unroll
        for (int k = 0; k < FBK; ++k) {
            float4 xa = *reinterpret_cast<const float4*>(&xs[k * XPITCH + row0]);
            float4 xb = *reinterpret_cast<const float4*>(&xs[k * XPITCH + row0 + 4]);
            float4 wv = *reinterpret_cast<const float4*>(&wst[k * FBN + col0]);
            float xf[8] = {xa.x, xa.y, xa.z, xa.w, xb.x, xb.y, xb.z, xb.w};
            float wf[4] = {wv.x, wv.y, wv.z, wv.w};
            #pragma unroll
            for (int i = 0; i < 8; ++i)
                #pragma unroll
                for (int j = 0; j < 4; ++j)
                    acc[i][j] = fmaf(xf[i], wf[j], acc[i][j]);
        }
    }
    __syncthreads();
    #pragma unroll
    for (int i = 0; i < 8; ++i) {
        float4 v = make_float4(acc[i][0], acc[i][1], acc[i][2], acc[i][3]);
        *reinterpret_cast<float4*>(&smem[(row0 + i) * FBN + col0]) = v;
    }
    __syncthreads();
    const int wave = tid >> 6;
    const int lane = tid & 63;
    const float br = b_route[lane];
    const float bnv = b_noise[lane];
    float ps_l = 0.f, fr_l = 0.f, l2_l = 0.f;
    for (int tt = 0; tt < FBM / 4; ++tt) {
        const int tok = wave * (FBM / 4) + tt;
        const int gt  = block_m + tok;
        float lr = smem[tok * FBN + lane] + br;
        float ln = smem[tok * FBN + NX + lane] + bnv;
        float nz = noise[(size_t)gt * NX + lane];
        float sp = fmaxf(ln, 0.f) + log1pf(expf(-fabsf(ln)));
        float v  = lr + nz * sp;
        float vv = v;
        float tv[9]; int ti[9];
        #pragma unroll
        for (int s = 0; s < 9; ++s) {
            float mv = vv; int mi = lane;
            #pragma unroll
            for (int off = 32; off > 0; off >>= 1) {
                float ov = __shfl_xor(mv, off);
                int   oi = __shfl_xor(mi, off);
                if (ov > mv || (ov == mv && oi < mi)) { mv = ov; mi = oi; }
            }
            tv[s] = mv; ti[s] = mi;
            if (lane == mi) vv = neginf();
        }
        float ming = 1e30f;
        #pragma unroll
        for (int s = 0; s < 8; ++s) ming = fminf(ming, tv[s] - tv[s + 1]);
        if (lane == 0 && ming < DELTA_FP32) {
            int p = atomicAdd(flag_cnt, 1);
            if (p < MAXFLAG) flag_list[p] = gt;
        }
        const float m0 = tv[0];
        float e8[8], s8 = 0.f;
        #pragma unroll
        for (int s = 0; s < 8; ++s) { e8[s] = expf(tv[s] - m0); s8 += e8[s]; }
        float r = 0.f;
        #pragma unroll
        for (int s = 0; s < 8; ++s) if (ti[s] == lane) r = e8[s] / s8;
        out[(size_t)gt * NX + lane] = r;
        if (lane < TK) out[TI_OFF + (size_t)gt * TK + lane] = (float)ti[lane];
        float p = expf(v - m0);
        float s64 = p;
        #pragma unroll
        for (int off = 32; off > 0; off >>= 1) s64 += __shfl_xor(s64, off);
        ps_l += p / s64;
        if (lane == 0) { float lse = m0 + logf(s64); l2_l += lse * lse; }
        unsigned tm8 = 0;
        #pragma unroll
        for (int s = 0; s < 8; ++s) if (ti[s] < TK) tm8 |= (1u << ti[s]);
        #pragma unroll
        for (int s = 0; s < 8; ++s)
            if (ti[s] == lane && ((tm8 >> s) & 1u)) fr_l += 1.f;
    }
    atomicAdd(&ps_acc[lane], ps_l);
    atomicAdd(&fr_acc[lane], fr_l);
    if (lane == 0) atomicAdd(lse2_acc, l2_l);
}

// ---------------------------------------------------------------------------
// fp64 repair of near-tie tokens (verified r3-r15)
// ---------------------------------------------------------------------------
__global__ __launch_bounds__(256) void refine_kernel(
    const float* __restrict__ x, const float* __restrict__ w_route,
    const float* __restrict__ b_route, const float* __restrict__ w_noise,
    const float* __restrict__ b_noise, const float* __restrict__ noise,
    float* __restrict__ out, const int* __restrict__ flag_cnt,
    const int* __restrict__ flag_list)
{
    __shared__ double red[8][64];
    const int tid = threadIdx.x;
    const int lane = tid & 63, wq = tid >> 6;
    int nf = *flag_cnt; if (nf > MAXFLAG) nf = MAXFLAG;
    for (int fi = blockIdx.x; fi < nf; fi += gridDim.x) {
        const int gt = flag_list[fi];
        const float* xr = x + (size_t)gt * NE + wq * 1024;
        const float* wr = w_route + (size_t)wq * 1024 * NX;
        const float* wn = w_noise + (size_t)wq * 1024 * NX;
        double ar0 = 0, ar1 = 0, an0 = 0, an1 = 0;
        for (int k = 0; k < 1024; k += 2) {
            double x0 = xr[k], x1 = xr[k + 1];
            ar0 += x0 * (double)wr[(size_t)k * NX + lane];
            ar1 += x1 * (double)wr[(size_t)(k + 1) * NX + lane];
            an0 += x0 * (double)wn[(size_t)k * NX + lane];
            an1 += x1 * (double)wn[(size_t)(k + 1) * NX + lane];
        }
        red[wq * 2][lane]     = ar0 + ar1;
        red[wq * 2 + 1][lane] = an0 + an1;
        __syncthreads();
        if (tid < 64) {
            double lr = red[0][lane] + red[2][lane] + red[4][lane] + red[6][lane]
                      + (double)b_route[lane];
            double ln = red[1][lane] + red[3][lane] + red[5][lane] + red[7][lane]
                      + (double)b_noise[lane];
            double nz = (double)noise[(size_t)gt * NX + lane];
            double sp = (ln > 0.0) ? (ln + log1p(exp(-ln))) : log1p(exp(ln));
            double v  = lr + nz * sp;
            double vv = v;
            double tv[8]; int ti[8];
            #pragma unroll
            for (int s = 0; s < 8; ++s) {
                double mv = vv; int mi = lane;
                #pragma unroll
                for (int off = 32; off > 0; off >>= 1) {
                    double ov = __shfl_xor(mv, off);
                    int    oi = __shfl_xor(mi, off);
                    if (ov > mv || (ov == mv && oi < mi)) { mv = ov; mi = oi; }
                }
                tv[s] = mv; ti[s] = mi;
                if (lane == mi) vv = -1.0e300;
            }
            double m0 = tv[0], s8 = 0.0, e8[8];
            #pragma unroll
            for (int s = 0; s < 8; ++s) { e8[s] = exp(tv[s] - m0); s8 += e8[s]; }
            float r = 0.f;
            #pragma unroll
            for (int s = 0; s < 8; ++s) if (ti[s] == lane) r = (float)(e8[s] / s8);
            out[(size_t)gt * NX + lane] = r;
            if (lane < TK) out[TI_OFF + (size_t)gt * TK + lane] = (float)ti[lane];
        }
        __syncthreads();
    }
}

// ---------------------------------------------------------------------------
// finalize: deterministic reduce of per-block stats, compute aux loss
// ---------------------------------------------------------------------------
__global__ __launch_bounds__(512) void finalize_kernel(
    const float* __restrict__ ps_blk, const float* __restrict__ fr_blk,
    const float* __restrict__ lse2_blk, float* __restrict__ out)
{
    __shared__ float sps[8][64], sfr[8][64], sl2[512];
    const int t = threadIdx.x;
    const int e = t & 63, g = t >> 6;
    float a = 0.f, b = 0.f;
    for (int blk = g; blk < NBLK; blk += 8) {
        a += ps_blk[(size_t)blk * 64 + e];
        b += fr_blk[(size_t)blk * 64 + e];
    }
    sps[g][e] = a;
    sfr[g][e] = b;
    sl2[t] = lse2_blk[t];
    __syncthreads();
    if (t < 64) {
        float p = 0.f, f = 0.f;
        #pragma unroll
        for (int gg = 0; gg < 8; ++gg) { p += sps[gg][t]; f += sfr[gg][t]; }
        float z = 0.f;
        #pragma unroll
        for (int i = 0; i < 8; ++i) z += sl2[t * 8 + i];
        float sp = p, sf = f, sz = z;
        #pragma unroll
        for (int off = 32; off > 0; off >>= 1) {
            sp += __shfl_xor(sp, off);
            sf += __shfl_xor(sf, off);
            sz += __shfl_xor(sz, off);
        }
        float d = (p / fmaxf(sp, 1e-12f)) * (f / fmaxf(sf, 1e-12f));
        #pragma unroll
        for (int off = 32; off > 0; off >>= 1) d += __shfl_xor(d, off);
        if (t == 0)
            out[AUX_IDX] = 64.f * d + 0.1f * (sz / (float)NT);
    }
}

// ---------------------------------------------------------------------------
extern "C" void kernel_launch(void* const* d_in, const int* in_sizes, int n_in,
                              void* d_out, int out_size, void* d_ws, size_t ws_size,
                              hipStream_t stream) {
    const float* x       = (const float*)d_in[0];
    const float* w_route = (const float*)d_in[1];
    const float* b_route = (const float*)d_in[2];
    const float* w_noise = (const float*)d_in[3];
    const float* b_noise = (const float*)d_in[4];
    const float* noise   = (const float*)d_in[5];
    float* out = (float*)d_out;

    float* wsf = (float*)d_ws;
    int* flag_cnt  = (int*)wsf;
    int* flag_list = (int*)(wsf + 1);
    float* ps_blk   = wsf + PSB_IDX;
    float* fr_blk   = wsf + FRB_IDX;
    float* lse2_blk = wsf + L2B_IDX;

    // zero flag region (cnt + list)
    hipMemsetAsync(d_ws, 0, (size_t)(1 + MAXFLAG) * sizeof(int), stream);

    if (ws_size >= WS_NEED) {
        unsigned short* bpack = (unsigned short*)((char*)d_ws + BPACK_OFF);
        prep_w_kernel<<<128, 512, 0, stream>>>(w_route, w_noise, bpack);
        fused32_kernel<<<NBLK, 1024, 0, stream>>>(
            x, bpack, b_route, b_noise, noise, out,
            ps_blk, fr_blk, lse2_blk, flag_cnt, flag_list);
    } else {
        // fallback: zero whole stats region, atomic-accumulate into row 0
        hipMemsetAsync(ps_blk, 0,
                       (size_t)(WS_FLOATS - PSB_IDX) * sizeof(float), stream);
        fused_router_kernel<<<NT / FBM, 256, 0, stream>>>(
            x, w_route, b_route, w_noise, b_noise, noise, out,
            ps_blk, fr_blk, lse2_blk, flag_cnt, flag_list);
    }

    refine_kernel<<<1024, 256, 0, stream>>>(
        x, w_route, b_route, w_noise, b_noise, noise, out, flag_cnt, flag_list);

    finalize_kernel<<<1, 512, 0, stream>>>(ps_blk, fr_blk, lse2_blk, out);
}